// Round 1
// baseline (151.713 us; speedup 1.0000x reference)
//
#include <hip/hip_runtime.h>

#define B_ 32
#define C_ 64
#define H_ 96
#define W_ 96
#define P_ 8
#define D_ 256
#define HP 89          // H - P + 1
#define L_ (HP * HP)   // 7921
#define HW (H_ * W_)   // 9216

// ---------------- Kernel 1: mean over channels ----------------
// x: (B, C, H, W) f32 -> xm: (B, H, W) f32
__global__ __launch_bounds__(256) void mean_kernel(const float* __restrict__ x,
                                                   float* __restrict__ xm) {
    int idx = blockIdx.x * blockDim.x + threadIdx.x;  // over B*HW/4
    if (idx >= B_ * HW / 4) return;
    int b   = idx / (HW / 4);
    int hw4 = idx % (HW / 4);
    const float4* p = (const float4*)(x + (size_t)b * C_ * HW) + hw4;
    float4 s = make_float4(0.f, 0.f, 0.f, 0.f);
#pragma unroll 4
    for (int c = 0; c < C_; ++c) {
        float4 v = p[(size_t)c * (HW / 4)];
        s.x += v.x; s.y += v.y; s.z += v.z; s.w += v.w;
    }
    const float inv = 1.0f / C_;
    s.x *= inv; s.y *= inv; s.z *= inv; s.w *= inv;
    ((float4*)xm)[idx] = s;
}

// ---------------- Kernel 2: patch extract + linear ----------------
// One block per (hp, b). 256 threads; thread t = output channel d.
// LDS: the 8x96 strip of xm rows hp..hp+7. W row per thread in registers.
// 4 patch positions per iteration: sliding-window register reuse.
__global__ __launch_bounds__(256) void patch_kernel(const float* __restrict__ xm,
                                                    const float* __restrict__ Wm,
                                                    const float* __restrict__ bias,
                                                    float* __restrict__ out) {
    __shared__ float rows[P_][112];   // 96 cols + pad for sliding-window overread
    const int hp = blockIdx.x;
    const int b  = blockIdx.y;
    const int t  = threadIdx.x;

    // stage the 8x96 strip
    const float* src = xm + (size_t)b * HW + (size_t)hp * W_;
    for (int i = t; i < P_ * W_; i += 256) {
        int r = i / W_, c = i % W_;
        rows[r][c] = src[r * W_ + c];
    }
    // zero the pad so FMAs on it are benign
    for (int i = t; i < P_ * 16; i += 256) {
        rows[i / 16][96 + (i % 16)] = 0.f;
    }

    // W row for this thread's output channel (64 floats = 16 float4)
    float w[64];
    const float4* wrow = (const float4*)(Wm + (size_t)t * 64);
#pragma unroll
    for (int i = 0; i < 16; ++i) ((float4*)w)[i] = wrow[i];
    const float bv = bias[t];

    __syncthreads();

    float* outp = out + ((size_t)b * L_ + (size_t)hp * HP) * D_ + t;

    for (int wp = 0; wp < HP; wp += 4) {
        float a0 = bv, a1 = bv, a2 = bv, a3 = bv;
#pragma unroll
        for (int r = 0; r < P_; ++r) {
            float col[11];
#pragma unroll
            for (int j = 0; j < 11; ++j) col[j] = rows[r][wp + j];
#pragma unroll
            for (int c = 0; c < P_; ++c) {
                const float wv = w[r * 8 + c];
                a0 = fmaf(col[c + 0], wv, a0);
                a1 = fmaf(col[c + 1], wv, a1);
                a2 = fmaf(col[c + 2], wv, a2);
                a3 = fmaf(col[c + 3], wv, a3);
            }
        }
        if (wp + 0 < HP) outp[(size_t)(wp + 0) * D_] = a0;
        if (wp + 1 < HP) outp[(size_t)(wp + 1) * D_] = a1;
        if (wp + 2 < HP) outp[(size_t)(wp + 2) * D_] = a2;
        if (wp + 3 < HP) outp[(size_t)(wp + 3) * D_] = a3;
    }
}

extern "C" void kernel_launch(void* const* d_in, const int* in_sizes, int n_in,
                              void* d_out, int out_size, void* d_ws, size_t ws_size,
                              hipStream_t stream) {
    const float* x    = (const float*)d_in[0];
    const float* Wm   = (const float*)d_in[1];
    const float* bias = (const float*)d_in[2];
    float* out = (float*)d_out;
    float* xm  = (float*)d_ws;   // B*H*W floats = 1.18 MB

    int n1 = B_ * HW / 4;  // 73728 threads
    mean_kernel<<<(n1 + 255) / 256, 256, 0, stream>>>(x, xm);

    dim3 grid(HP, B_);
    patch_kernel<<<grid, 256, 0, stream>>>(xm, Wm, bias, out);
}

// Round 2
// 82.923 us; speedup vs baseline: 1.8296x; 1.8296x over previous
//
#include <hip/hip_runtime.h>
#include <hip/hip_bf16.h>

#define B_ 32
#define C_ 64
#define H_ 96
#define W_ 96
#define P_ 8
#define D_ 256
#define HP 89          // H - P + 1
#define L_ (HP * HP)   // 7921
#define HW (H_ * W_)   // 9216

typedef __attribute__((ext_vector_type(8))) short bf16x8;
typedef __attribute__((ext_vector_type(4))) float f32x4;

static __device__ inline short f2bf(float f) {
    union { float f; unsigned u; } v; v.f = f;
    unsigned r = v.u + 0x7FFFu + ((v.u >> 16) & 1u);   // round-to-nearest-even
    return (short)(r >> 16);
}

// ---------------- Kernel 1: mean over channels ----------------
__global__ __launch_bounds__(256) void mean_kernel(const float* __restrict__ x,
                                                   float* __restrict__ xm) {
    int idx = blockIdx.x * blockDim.x + threadIdx.x;  // over B*HW/4
    if (idx >= B_ * HW / 4) return;
    int b   = idx / (HW / 4);
    int hw4 = idx % (HW / 4);
    const float4* p = (const float4*)(x + (size_t)b * C_ * HW) + hw4;
    float4 s = make_float4(0.f, 0.f, 0.f, 0.f);
#pragma unroll 4
    for (int c = 0; c < C_; ++c) {
        float4 v = p[(size_t)c * (HW / 4)];
        s.x += v.x; s.y += v.y; s.z += v.z; s.w += v.w;
    }
    const float inv = 1.0f / C_;
    s.x *= inv; s.y *= inv; s.z *= inv; s.w *= inv;
    ((float4*)xm)[idx] = s;
}

// ---------------- Kernel 2: convert W (256x64 f32) -> bf16 ----------------
__global__ __launch_bounds__(256) void wcvt_kernel(const float* __restrict__ Wm,
                                                   short* __restrict__ Wb) {
    int i = blockIdx.x * 256 + threadIdx.x;   // over 16384/4 = 4096
    if (i >= D_ * P_ * P_ / 4) return;
    float4 v = ((const float4*)Wm)[i];
    short4 o;
    o.x = f2bf(v.x); o.y = f2bf(v.y); o.z = f2bf(v.z); o.w = f2bf(v.w);
    ((short4*)Wb)[i] = o;
}

// ---------------- Kernel 3: patch GEMM via MFMA ----------------
// Block = (hp, b), 256 threads = 4 waves. M = 96 (89 valid positions, 6 tiles
// of 16), N = 256 (wave w owns cols [w*64, w*64+64), 4 n-tiles), K = 64.
// A[m][k] = strip[k/8][m + k%8] (im2col on the fly), B[k][n] = W[n][k].
__global__ __launch_bounds__(256) void gemm_kernel(const float* __restrict__ xm,
                                                   const short* __restrict__ Wb,
                                                   const float* __restrict__ bias,
                                                   float* __restrict__ out) {
    __shared__ float strip[P_][112];   // stride 112: lane-groups alias banks 2-way (free)
    const int hp   = blockIdx.x;
    const int b    = blockIdx.y;
    const int t    = threadIdx.x;
    const int wave = t >> 6;
    const int lane = t & 63;
    const int l15  = lane & 15;
    const int lg   = lane >> 4;       // lane group 0..3
    const int n0   = wave * 64;

    // stage the 8x96 strip; zero cols 96..111 (read by padding rows, never stored)
    const float* src = xm + (size_t)b * HW + (size_t)hp * W_;
    for (int i = t; i < P_ * 112; i += 256) {
        int r = i / 112, c = i % 112;
        strip[r][c] = (c < W_) ? src[r * W_ + c] : 0.f;
    }

    // B fragments: lane holds B[k..k+7][n], n = n0 + nt*16 + l15, k = kh*32 + lg*8
    bf16x8 bfrag[2][4];
#pragma unroll
    for (int kh = 0; kh < 2; ++kh)
#pragma unroll
        for (int nt = 0; nt < 4; ++nt) {
            int n = n0 + nt * 16 + l15;
            int k = kh * 32 + lg * 8;
            bfrag[kh][nt] = *(const bf16x8*)(Wb + n * 64 + k);
        }

    // accumulators init = bias (all 4 regs of a tile share the same column d)
    f32x4 acc[6][4];
#pragma unroll
    for (int nt = 0; nt < 4; ++nt) {
        float bv = bias[n0 + nt * 16 + l15];
#pragma unroll
        for (int mt = 0; mt < 6; ++mt) acc[mt][nt] = f32x4{bv, bv, bv, bv};
    }

    __syncthreads();

#pragma unroll
    for (int kh = 0; kh < 2; ++kh) {
        // A fragments: k = kh*32 + lg*8 + j -> r = kh*4 + lg (fixed per lane), c = j
        const int r = kh * 4 + lg;
        bf16x8 afrag[6];
#pragma unroll
        for (int mt = 0; mt < 6; ++mt) {
            const int wp = mt * 16 + l15;
            bf16x8 a;
#pragma unroll
            for (int j = 0; j < 8; ++j) a[j] = f2bf(strip[r][wp + j]);
            afrag[mt] = a;
        }
#pragma unroll
        for (int nt = 0; nt < 4; ++nt)
#pragma unroll
            for (int mt = 0; mt < 6; ++mt)
                acc[mt][nt] = __builtin_amdgcn_mfma_f32_16x16x32_bf16(
                    afrag[mt], bfrag[kh][nt], acc[mt][nt], 0, 0, 0);
    }

    // store: D row = lg*4 + reg (wp within tile), col = l15 (d within n-tile)
    float* outp = out + ((size_t)b * L_ + (size_t)hp * HP) * D_ + n0 + l15;
#pragma unroll
    for (int mt = 0; mt < 6; ++mt)
#pragma unroll
        for (int rg = 0; rg < 4; ++rg) {
            const int wp = mt * 16 + lg * 4 + rg;
            if (wp < HP) {
#pragma unroll
                for (int nt = 0; nt < 4; ++nt)
                    outp[(size_t)wp * D_ + nt * 16] = acc[mt][nt][rg];
            }
        }
}

extern "C" void kernel_launch(void* const* d_in, const int* in_sizes, int n_in,
                              void* d_out, int out_size, void* d_ws, size_t ws_size,
                              hipStream_t stream) {
    const float* x    = (const float*)d_in[0];
    const float* Wm   = (const float*)d_in[1];
    const float* bias = (const float*)d_in[2];
    float* out = (float*)d_out;

    float* xm = (float*)d_ws;                       // B*H*W f32 = 1.18 MB
    short* Wb = (short*)((char*)d_ws + (size_t)B_ * HW * sizeof(float)); // 32 KB

    int n1 = B_ * HW / 4;
    mean_kernel<<<(n1 + 255) / 256, 256, 0, stream>>>(x, xm);
    wcvt_kernel<<<16, 256, 0, stream>>>(Wm, Wb);

    dim3 grid(HP, B_);
    gemm_kernel<<<grid, 256, 0, stream>>>(xm, Wb, bias, out);
}

// Round 3
// 80.218 us; speedup vs baseline: 1.8912x; 1.0337x over previous
//
#include <hip/hip_runtime.h>
#include <hip/hip_bf16.h>

#define B_ 32
#define C_ 64
#define H_ 96
#define W_ 96
#define P_ 8
#define D_ 256
#define HP 89          // H - P + 1
#define L_ (HP * HP)   // 7921
#define HW (H_ * W_)   // 9216

#define SW 72          // LDS row stride in u32 words (72 % 32 == 8 -> bank spread)
#define COPY (P_ * SW) // 576 words per parity copy

typedef __attribute__((ext_vector_type(8))) short bf16x8;
typedef __attribute__((ext_vector_type(4))) float f32x4;

static __device__ inline unsigned f2bf_u(float f) {
    union { float f; unsigned u; } v; v.f = f;
    return (v.u + 0x7FFFu + ((v.u >> 16) & 1u)) >> 16;   // RNE, as u32
}

// ------------- Kernel 1: mean over channels (+ W convert in tail blocks) ----
__global__ __launch_bounds__(256) void mean_kernel(const float* __restrict__ x,
                                                   float* __restrict__ xm,
                                                   const float* __restrict__ Wm,
                                                   unsigned short* __restrict__ Wb) {
    if (blockIdx.x >= (B_ * HW / 4) / 256) {
        // tail blocks: convert W (256x64 f32 -> bf16), 4096 float4s over 16 blocks
        int i = (blockIdx.x - (B_ * HW / 4) / 256) * 256 + threadIdx.x;
        if (i < D_ * P_ * P_ / 4) {
            float4 v = ((const float4*)Wm)[i];
            ushort4 o;
            o.x = (unsigned short)f2bf_u(v.x);
            o.y = (unsigned short)f2bf_u(v.y);
            o.z = (unsigned short)f2bf_u(v.z);
            o.w = (unsigned short)f2bf_u(v.w);
            ((ushort4*)Wb)[i] = o;
        }
        return;
    }
    int idx = blockIdx.x * blockDim.x + threadIdx.x;  // over B*HW/4
    int b   = idx / (HW / 4);
    int hw4 = idx % (HW / 4);
    const float4* p = (const float4*)(x + (size_t)b * C_ * HW) + hw4;
    float4 s = make_float4(0.f, 0.f, 0.f, 0.f);
#pragma unroll 4
    for (int c = 0; c < C_; ++c) {
        float4 v = p[(size_t)c * (HW / 4)];
        s.x += v.x; s.y += v.y; s.z += v.z; s.w += v.w;
    }
    const float inv = 1.0f / C_;
    s.x *= inv; s.y *= inv; s.z *= inv; s.w *= inv;
    ((float4*)xm)[idx] = s;
}

// ---------------- Kernel 2: patch GEMM via MFMA ----------------
// Block = (hp, b), 256 threads = 4 waves. M = 96 (89 valid), N = 256
// (wave w owns cols [w*64, w*64+64)), K = 64. A built from a bf16 strip in
// LDS stored as TWO parity-shifted packed-u32 copies so the stride-1 sliding
// window becomes 4 aligned ds_read_b32 per fragment.
__global__ __launch_bounds__(256) void gemm_kernel(const float* __restrict__ xm,
                                                   const unsigned short* __restrict__ Wb,
                                                   const float* __restrict__ bias,
                                                   float* __restrict__ out) {
    __shared__ unsigned strip[2 * COPY];   // [copy][row][word] = 4608 B
    const int hp   = blockIdx.x;
    const int b    = blockIdx.y;
    const int t    = threadIdx.x;
    const int wave = t >> 6;
    const int lane = t & 63;
    const int l15  = lane & 15;
    const int lg   = lane >> 4;       // lane group 0..3
    const int n0   = wave * 64;

    // ---- stage: bf16 strip, two parity copies, packed pairs into u32 ----
    // copy 0 (even): word c2 = cols (2c2, 2c2+1); copy 1 (odd): cols (2c2+1, 2c2+2)
    const float* src = xm + (size_t)b * HW + (size_t)hp * W_;
    for (int i = t; i < 2 * COPY; i += 256) {
        int cp  = i / COPY;
        int rem = i - cp * COPY;
        int r   = rem / SW;
        int c2  = rem - r * SW;
        int c0  = 2 * c2 + cp;
        int c1  = c0 + 1;
        float v0 = (c0 < W_) ? src[r * W_ + c0] : 0.f;
        float v1 = (c1 < W_) ? src[r * W_ + c1] : 0.f;
        strip[i] = f2bf_u(v0) | (f2bf_u(v1) << 16);
    }

    // ---- B fragments: lane holds B[k..k+7][n], n = n0+nt*16+l15, k = kh*32+lg*8
    bf16x8 bfrag[2][4];
#pragma unroll
    for (int kh = 0; kh < 2; ++kh)
#pragma unroll
        for (int nt = 0; nt < 4; ++nt) {
            int n = n0 + nt * 16 + l15;
            int k = kh * 32 + lg * 8;
            bfrag[kh][nt] = *(const bf16x8*)(Wb + n * 64 + k);
        }

    // ---- accumulators init = bias ----
    f32x4 acc[6][4];
#pragma unroll
    for (int nt = 0; nt < 4; ++nt) {
        float bv = bias[n0 + nt * 16 + l15];
#pragma unroll
        for (int mt = 0; mt < 6; ++mt) acc[mt][nt] = f32x4{bv, bv, bv, bv};
    }

    __syncthreads();

    // per-lane LDS base: parity copy + row lg + word (l15>>1)
    const unsigned* base = strip + (l15 & 1) * COPY + lg * SW + (l15 >> 1);

#pragma unroll
    for (int kh = 0; kh < 2; ++kh) {
        bf16x8 afrag[6];
#pragma unroll
        for (int mt = 0; mt < 6; ++mt) {
            union { uint4 u; bf16x8 s; } a;
            const unsigned* p = base + kh * (4 * SW) + mt * 8;
            a.u.x = p[0]; a.u.y = p[1]; a.u.z = p[2]; a.u.w = p[3];
            afrag[mt] = a.s;
        }
#pragma unroll
        for (int nt = 0; nt < 4; ++nt)
#pragma unroll
            for (int mt = 0; mt < 6; ++mt)
                acc[mt][nt] = __builtin_amdgcn_mfma_f32_16x16x32_bf16(
                    afrag[mt], bfrag[kh][nt], acc[mt][nt], 0, 0, 0);
    }

    // ---- store: row = lg*4 + reg (wp within tile), col = l15 within n-tile
    float* outp = out + ((size_t)b * L_ + (size_t)hp * HP) * D_ + n0 + l15;
#pragma unroll
    for (int mt = 0; mt < 6; ++mt)
#pragma unroll
        for (int rg = 0; rg < 4; ++rg) {
            const int wp = mt * 16 + lg * 4 + rg;
            if (wp < HP) {
#pragma unroll
                for (int nt = 0; nt < 4; ++nt)
                    outp[(size_t)wp * D_ + nt * 16] = acc[mt][nt][rg];
            }
        }
}

extern "C" void kernel_launch(void* const* d_in, const int* in_sizes, int n_in,
                              void* d_out, int out_size, void* d_ws, size_t ws_size,
                              hipStream_t stream) {
    const float* x    = (const float*)d_in[0];
    const float* Wm   = (const float*)d_in[1];
    const float* bias = (const float*)d_in[2];
    float* out = (float*)d_out;

    float* xm = (float*)d_ws;                                              // 1.18 MB
    unsigned short* Wb = (unsigned short*)((char*)d_ws + (size_t)B_ * HW * sizeof(float)); // 32 KB

    int nblk = (B_ * HW / 4) / 256 + 16;   // 288 mean blocks + 16 W-convert blocks
    mean_kernel<<<nblk, 256, 0, stream>>>(x, xm, Wm, Wb);

    dim3 grid(HP, B_);
    gemm_kernel<<<grid, 256, 0, stream>>>(xm, Wb, bias, out);
}